// Round 4
// baseline (1927.314 us; speedup 1.0000x reference)
//
#include <hip/hip_runtime.h>
#include <cstdint>

#define NIN     2000
#define NRES    50
#define NOUT    500
#define TSTEPS  512
#define NBATCH  64

#define CHUNK   512     // padded k-chunk (500 valid + 12 zero cols)
#define KVALID  500
#define NCHUNK  4

// tanh(x) = 1 - 2/(e^{2x}+1). Overflow-safe: x>>0 -> 1, x<<0 -> -1. No NaN path.
__device__ __forceinline__ float fast_tanh(float x) {
  float e = __expf(2.0f * x);
  return fmaf(-2.0f, __builtin_amdgcn_rcpf(e + 1.0f), 1.0f);
}

// ---- kernel 1: P[t][b][i] = sum_k tanh(u[b,t,k]) * W_in[i][k] ----
// grid (128, 2): x = 256-row block of U, y = 25-row half of W_in.
// block = 256 thr = 4 waves; wave rg covers rows x*256 + rg*64 + lane.
// W chunk lives in LDS (wave-uniform broadcast reads, off the VALU pipe);
// U is a per-lane coalesced float4 stream with a distance-2 prefetch ring.
// No atomics: each (row, i-half) is written exactly once, 25 contiguous floats.
__global__ __launch_bounds__(256) void proj_kernel(const float* __restrict__ U,
                                                   const float* __restrict__ Win,
                                                   float* __restrict__ P) {
  __shared__ __align__(16) float Wlds[25 * CHUNK];

  const int rg    = threadIdx.x >> 6;
  const int lane  = threadIdx.x & 63;
  const int row   = blockIdx.x * 256 + rg * 64 + lane;   // row = b*512 + t
  const int ibase = blockIdx.y * 25;

  const float* __restrict__ u = U + (size_t)row * NIN;

  float acc[25];
#pragma unroll
  for (int i = 0; i < 25; ++i) acc[i] = 0.f;

  for (int c = 0; c < NCHUNK; ++c) {
    const int kb = c * KVALID;

    __syncthreads();   // previous chunk's readers done before overwrite
    for (int idx = threadIdx.x; idx < 25 * CHUNK; idx += 256) {
      int il = idx >> 9;            // / CHUNK
      int kc = idx & (CHUNK - 1);
      Wlds[idx] = (kc < KVALID) ? Win[(size_t)(ibase + il) * NIN + kb + kc] : 0.f;
    }
    __syncthreads();

    // U prefetch ring, distance 2 octs. Clamped addresses only bite where the
    // padded W columns are zero, so wrong-but-finite values contribute nothing.
    float4 ca[2], cb[2];
#pragma unroll
    for (int d = 0; d < 2; ++d) {
      int ko = kb + d * 8;
      ca[d] = *reinterpret_cast<const float4*>(u + min(ko, NIN - 4));
      cb[d] = *reinterpret_cast<const float4*>(u + min(ko + 4, NIN - 4));
    }

#pragma unroll 4
    for (int oct = 0; oct < CHUNK / 8; ++oct) {
      float4 c0 = ca[oct & 1], c1 = cb[oct & 1];
      float t[8];
      t[0] = fast_tanh(c0.x); t[1] = fast_tanh(c0.y);
      t[2] = fast_tanh(c0.z); t[3] = fast_tanh(c0.w);
      t[4] = fast_tanh(c1.x); t[5] = fast_tanh(c1.y);
      t[6] = fast_tanh(c1.z); t[7] = fast_tanh(c1.w);

      if (oct + 2 < CHUNK / 8) {
        int kn = kb + (oct + 2) * 8;
        ca[oct & 1] = *reinterpret_cast<const float4*>(u + min(kn, NIN - 4));
        cb[oct & 1] = *reinterpret_cast<const float4*>(u + min(kn + 4, NIN - 4));
      }

      const float4* wl = reinterpret_cast<const float4*>(Wlds) + oct * 2;
#pragma unroll
      for (int i = 0; i < 25; ++i) {
        float4 w0 = wl[i * (CHUNK / 4)];
        float4 w1 = wl[i * (CHUNK / 4) + 1];
        acc[i] = fmaf(t[0], w0.x, acc[i]);
        acc[i] = fmaf(t[1], w0.y, acc[i]);
        acc[i] = fmaf(t[2], w0.z, acc[i]);
        acc[i] = fmaf(t[3], w0.w, acc[i]);
        acc[i] = fmaf(t[4], w1.x, acc[i]);
        acc[i] = fmaf(t[5], w1.y, acc[i]);
        acc[i] = fmaf(t[6], w1.z, acc[i]);
        acc[i] = fmaf(t[7], w1.w, acc[i]);
      }
    }
  }

  const int t = row & (TSTEPS - 1);
  const int b = row >> 9;
  float* Pr = P + (((size_t)t * NBATCH + b) << 6) + ibase;   // 25 contiguous floats
#pragma unroll
  for (int i = 0; i < 25; ++i) Pr[i] = acc[i];
}

// ---- kernel 2: recurrence + fused readout. 64 blocks x 1 wave; wave = batch. ----
// lane i holds W_res row i in VGPRs; state broadcast via private-LDS round-trip
// (1 ds_write + 12 uniform ds_read_b128 per step). No barriers -> the P
// prefetch ring (depth 4, coalesced 256B loads) never drains.
__global__ __launch_bounds__(64) void recur_kernel(const float* __restrict__ P,
                                                   const float* __restrict__ W_res,
                                                   const float* __restrict__ W_out,
                                                   const float* __restrict__ bias,
                                                   float* __restrict__ out) {
  __shared__ __align__(16) float s[52];
  const int b  = blockIdx.x;
  const int i  = threadIdx.x;
  const int ic = (i < NRES) ? i : (NRES - 1);

  float w[NRES];
#pragma unroll
  for (int j = 0; j < NRES; ++j) w[j] = W_res[ic * NRES + j];

  if (i < 52) s[i] = 0.f;

  float pr[4];
#pragma unroll
  for (int d = 0; d < 4; ++d)
    pr[d] = P[(((size_t)d * NBATCH + b) << 6) + i];

  const float4* s4 = reinterpret_cast<const float4*>(s);

  for (int t = 0; t < TSTEPS; ++t) {
    float y = pr[t & 3];
    if (t + 4 < TSTEPS)
      pr[t & 3] = P[(((size_t)(t + 4) * NBATCH + b) << 6) + i];

    float a0 = y, a1 = 0.f, a2 = 0.f, a3 = 0.f;
#pragma unroll
    for (int q = 0; q < 12; ++q) {
      float4 sv = s4[q];                 // wave-uniform broadcast
      a0 = fmaf(w[4 * q + 0], sv.x, a0);
      a1 = fmaf(w[4 * q + 1], sv.y, a1);
      a2 = fmaf(w[4 * q + 2], sv.z, a2);
      a3 = fmaf(w[4 * q + 3], sv.w, a3);
    }
    a0 = fmaf(w[48], s[48], a0);
    a1 = fmaf(w[49], s[49], a1);

    float ns = fast_tanh((a0 + a1) + (a2 + a3));
    if (i < NRES) s[i] = ns;             // single wave: in-order LDS, no barrier
  }

  // readout: out[b][o] = tanh(sum_j s[j] * W_out[j][o] + bias[o])
#pragma unroll
  for (int rnd = 0; rnd < 8; ++rnd) {
    int o = rnd * 64 + i;
    if (o < NOUT) {
      float a0 = bias[o], a1 = 0.f;
#pragma unroll
      for (int j = 0; j < NRES; j += 2) {
        a0 = fmaf(s[j],     W_out[j * NOUT + o],       a0);
        a1 = fmaf(s[j + 1], W_out[(j + 1) * NOUT + o], a1);
      }
      out[b * NOUT + o] = fast_tanh(a0 + a1);
    }
  }
}

extern "C" void kernel_launch(void* const* d_in, const int* in_sizes, int n_in,
                              void* d_out, int out_size, void* d_ws, size_t ws_size,
                              hipStream_t stream) {
  const float* inputs = (const float*)d_in[0];
  const float* W_in   = (const float*)d_in[1];
  const float* W_res  = (const float*)d_in[2];
  const float* W_out  = (const float*)d_in[3];
  const float* bias   = (const float*)d_in[4];
  float* out = (float*)d_out;

  // ws: P[512][64][64] f32 = 8.39 MB (i padded 50->64; pad never touched)
  float* P = (float*)d_ws;

  proj_kernel<<<dim3(128, 2), 256, 0, stream>>>(inputs, W_in, P);
  recur_kernel<<<NBATCH, 64, 0, stream>>>(P, W_res, W_out, bias, out);
}